// Round 2
// baseline (2925.827 us; speedup 1.0000x reference)
//
#include <hip/hip_runtime.h>
#include <math.h>

typedef _Float16 h2_t __attribute__((ext_vector_type(2)));
typedef _Float16 h4_t __attribute__((ext_vector_type(4)));

#define T_ 512
#define B_ 64
#define E_ 256
#define H_ 256
#define G_ 1024   // 4*H
#define K_ 16
#define NEG_ (-10000.0f)
#define START_ 14
#define STOP_ 15

#if defined(__has_builtin)
#if __has_builtin(__builtin_amdgcn_fdot2)
#define HAVE_FDOT2 1
#endif
#endif

static __device__ __forceinline__ float dot2(h2_t a, h2_t b, float c) {
#ifdef HAVE_FDOT2
    return __builtin_amdgcn_fdot2(a, b, c, false);
#else
    return fmaf((float)a[0], (float)b[0], fmaf((float)a[1], (float)b[1], c));
#endif
}

// ---------------------------------------------------------------------------
// Kernel A: input-gate GEMM (both directions fused along N), fp32 math,
// fp16 store.  gin_d[t][b][n] = sum_k emb[sent(b,t), k] * w_ih_d[n, k]
// M = 32768 (m = t*64 + b), N = 2048 (n<1024 fwd, else bwd), K = 256.
// Bias is NOT added here (recurrence adds it).
// ---------------------------------------------------------------------------
__global__ __launch_bounds__(256)
void gates_gemm(const int* __restrict__ sentence,
                const float* __restrict__ emb,
                const float* __restrict__ w_ih_f,
                const float* __restrict__ w_ih_b,
                _Float16* __restrict__ gin_f,
                _Float16* __restrict__ gin_b)
{
    __shared__ float As[16][64];
    __shared__ float Bs[16][64];
    __shared__ int   ebase[64];

    const int bm  = blockIdx.x;      // 0..511   (M tiles of 64 = one t each)
    const int bn  = blockIdx.y;      // 0..31    (N tiles of 64)
    const int tid = threadIdx.x;

    const int dir = (bn * 64) >> 10;                  // uniform per block
    const float*   __restrict__ wih  = dir ? w_ih_b : w_ih_f;
    _Float16*      __restrict__ gout = dir ? gin_b : gin_f;
    const int nb = (bn * 64) & 1023;                  // local col base

    if (tid < 64) {
        int m = bm * 64 + tid;
        int t = m >> 6, bb = m & 63;
        ebase[tid] = sentence[bb * T_ + t] * E_;
    }
    __syncthreads();

    const int lr = tid >> 2;          // 0..63
    const int lc = (tid & 3) * 4;     // 0,4,8,12
    const int tx = tid & 15;
    const int ty = tid >> 4;

    float acc[4][4];
    #pragma unroll
    for (int i = 0; i < 4; ++i)
        #pragma unroll
        for (int j = 0; j < 4; ++j) acc[i][j] = 0.f;

    for (int kt = 0; kt < 256; kt += 16) {
        float4 av = *(const float4*)(emb + ebase[lr] + kt + lc);
        float4 bv = *(const float4*)(wih + (nb + lr) * 256 + kt + lc);
        As[lc + 0][lr] = av.x; As[lc + 1][lr] = av.y;
        As[lc + 2][lr] = av.z; As[lc + 3][lr] = av.w;
        Bs[lc + 0][lr] = bv.x; Bs[lc + 1][lr] = bv.y;
        Bs[lc + 2][lr] = bv.z; Bs[lc + 3][lr] = bv.w;
        __syncthreads();
        #pragma unroll
        for (int c = 0; c < 16; ++c) {
            float4 a4 = ((const float4*)As[c])[ty];
            float4 b4 = ((const float4*)Bs[c])[tx];
            float aa[4] = {a4.x, a4.y, a4.z, a4.w};
            float bb[4] = {b4.x, b4.y, b4.z, b4.w};
            #pragma unroll
            for (int i = 0; i < 4; ++i)
                #pragma unroll
                for (int j = 0; j < 4; ++j)
                    acc[i][j] = fmaf(aa[i], bb[j], acc[i][j]);
        }
        __syncthreads();
    }

    #pragma unroll
    for (int i = 0; i < 4; ++i) {
        int m = bm * 64 + ty * 4 + i;
        h4_t pk;
        pk[0] = (_Float16)acc[i][0];
        pk[1] = (_Float16)acc[i][1];
        pk[2] = (_Float16)acc[i][2];
        pk[3] = (_Float16)acc[i][3];
        *(h4_t*)(gout + (size_t)m * 1024 + nb + tx * 4) = pk;
    }
}

// ---------------------------------------------------------------------------
// Kernel B: persistent LSTM recurrence. 128 blocks = (dir, b). 512 threads
// (8 waves, 2/SIMD -> 256 VGPR cap). Thread q owns gate rows {q, q+512} as
// packed fp16 (2 x 128 half2 = 256 VGPRs), accumulates with v_dot2_f32_f16.
// h broadcast via LDS as half2; c in a register of thread u<256.
// ---------------------------------------------------------------------------
__global__ __launch_bounds__(512)
void lstm_persist(const _Float16* __restrict__ gin_f,
                  const _Float16* __restrict__ gin_b,
                  const float* __restrict__ w_hh_f,
                  const float* __restrict__ w_hh_b,
                  const float* __restrict__ b_f,
                  const float* __restrict__ b_b,
                  float* __restrict__ hf, float* __restrict__ hb)
{
    __shared__ h2_t  h2buf[128];     // 256 h values, packed
    __shared__ float gbuf[1024];

    const int blk = blockIdx.x;
    const int dir = blk >> 6;
    const int b   = blk & 63;
    const int q   = threadIdx.x;     // 0..511

    const _Float16* __restrict__ gin = dir ? gin_b : gin_f;
    const float*    __restrict__ whh = dir ? w_hh_b : w_hh_f;
    const float*    __restrict__ bs  = dir ? b_b : b_f;
    float*          __restrict__ hout = dir ? hb : hf;

    // load + convert weights for rows q and q+512
    h2_t w0[128], w1[128];
    {
        const float2* r0 = (const float2*)(whh + (size_t)q * 256);
        const float2* r1 = (const float2*)(whh + (size_t)(q + 512) * 256);
        #pragma unroll
        for (int k = 0; k < 128; ++k) {
            float2 a = r0[k];
            float2 c2 = r1[k];
            h2_t pa, pb;
            pa[0] = (_Float16)a.x;  pa[1] = (_Float16)a.y;
            pb[0] = (_Float16)c2.x; pb[1] = (_Float16)c2.y;
            w0[k] = pa; w1[k] = pb;
        }
    }
    const float bias0 = bs[q];
    const float bias1 = bs[q + 512];

    if (q < 128) { h2_t z; z[0] = (_Float16)0.f; z[1] = (_Float16)0.f; h2buf[q] = z; }
    float c = 0.f;
    __syncthreads();

    const long tstr = 64 * 1024;                 // gin halves per t
    const long hstr = 64 * 256;                  // h floats per t
    const _Float16* gp = gin + (size_t)(dir ? 511 : 0) * tstr + (size_t)b * 1024 + q;
    float*          hp = hout + (size_t)(dir ? 511 : 0) * hstr + (size_t)b * 256 + q;
    const long gstep = dir ? -tstr : tstr;
    const long hstep = dir ? -hstr : hstr;

    union U4 { float4 f; h2_t h[4]; };

    for (int s = 0; s < T_; ++s) {
        float a0 = bias0 + (float)gp[0];
        float a1 = bias1 + (float)gp[512];
        #pragma unroll
        for (int k4 = 0; k4 < 32; ++k4) {
            U4 u;
            u.f = ((const float4*)h2buf)[k4];    // wave-uniform broadcast, b128
            a0 = dot2(w0[4 * k4 + 0], u.h[0], a0);
            a1 = dot2(w1[4 * k4 + 0], u.h[0], a1);
            a0 = dot2(w0[4 * k4 + 1], u.h[1], a0);
            a1 = dot2(w1[4 * k4 + 1], u.h[1], a1);
            a0 = dot2(w0[4 * k4 + 2], u.h[2], a0);
            a1 = dot2(w1[4 * k4 + 2], u.h[2], a1);
            a0 = dot2(w0[4 * k4 + 3], u.h[3], a0);
            a1 = dot2(w1[4 * k4 + 3], u.h[3], a1);
        }
        gbuf[q] = a0;
        gbuf[q + 512] = a1;
        __syncthreads();
        if (q < 256) {
            float gi = gbuf[q], gf = gbuf[q + 256], gg = gbuf[q + 512], go = gbuf[q + 768];
            float si = 1.f / (1.f + expf(-gi));
            float sf = 1.f / (1.f + expf(-gf));
            float so = 1.f / (1.f + expf(-go));
            c = sf * c + si * tanhf(gg);
            float h = so * tanhf(c);
            hp[0] = h;
            ((_Float16*)h2buf)[q] = (_Float16)h;
        }
        gp += gstep;
        hp += hstep;
        __syncthreads();
    }
}

// ---------------------------------------------------------------------------
// Kernel C: feats[m, o] = concat(hf[m], hb[m]) . w_out[o, :] + b_out[o]
// One wave per row m; lane = (o, quarter-of-K). fp32.
// ---------------------------------------------------------------------------
__global__ __launch_bounds__(256)
void feats_proj(const float* __restrict__ hf, const float* __restrict__ hb,
                const float* __restrict__ w_out, const float* __restrict__ b_out,
                float* __restrict__ feats)
{
    const int lane = threadIdx.x & 63;
    const int wv   = threadIdx.x >> 6;
    const int m    = blockIdx.x * 4 + wv;
    const int o    = lane & 15;
    const int q    = lane >> 4;

    const float* hsrc = (q < 2) ? (hf + (size_t)m * 256 + q * 128)
                                : (hb + (size_t)m * 256 + (q - 2) * 128);
    const float4* h4 = (const float4*)hsrc;
    const float4* w4 = (const float4*)(w_out + o * 512 + q * 128);

    float acc = 0.f;
    #pragma unroll
    for (int i = 0; i < 32; ++i) {
        float4 hv = h4[i], wvv = w4[i];
        acc = fmaf(hv.x, wvv.x, acc);
        acc = fmaf(hv.y, wvv.y, acc);
        acc = fmaf(hv.z, wvv.z, acc);
        acc = fmaf(hv.w, wvv.w, acc);
    }
    acc += __shfl_xor(acc, 16, 64);
    acc += __shfl_xor(acc, 32, 64);
    if (lane < 16) feats[(size_t)m * 16 + o] = acc + b_out[o];
}

// ---------------------------------------------------------------------------
// Kernel D: Viterbi + backtrace. One wave per batch element.
// ---------------------------------------------------------------------------
__global__ __launch_bounds__(64)
void viterbi(const float* __restrict__ feats, const float* __restrict__ trans,
             float* __restrict__ out)
{
    __shared__ unsigned char bp[T_][16];
    const int b    = blockIdx.x;
    const int lane = threadIdx.x;

    float tr[16];
    #pragma unroll
    for (int p = 0; p < 16; ++p)
        tr[p] = (lane < 16) ? trans[lane * 16 + p] : 0.f;

    float fv = (lane == START_) ? 0.f : NEG_;

    for (int t = 0; t < T_; ++t) {
        float best = -3.4e38f; int arg = 0;
        #pragma unroll
        for (int p = 0; p < 16; ++p) {
            float s = __shfl(fv, p, 64) + tr[p];
            if (s > best) { best = s; arg = p; }   // strict > keeps first index
        }
        float ft = (lane < 16) ? feats[((size_t)t * 64 + b) * 16 + lane] : 0.f;
        if (lane < 16) {
            fv = best + ft;
            bp[t][lane] = (unsigned char)arg;
        }
    }

    float term = fv + ((lane < 16) ? trans[STOP_ * 16 + lane] : 0.f);
    float v  = (lane < 16) ? term : -3.4e38f;
    int  idx = (lane < 16) ? lane : (1 << 20);
    #pragma unroll
    for (int off = 1; off < 64; off <<= 1) {
        float v2 = __shfl_xor(v, off, 64);
        int   i2 = __shfl_xor(idx, off, 64);
        if (v2 > v || (v2 == v && i2 < idx)) { v = v2; idx = i2; }
    }
    __syncthreads();
    if (lane == 0) {
        out[b] = v;                              // best_score
        int tag = idx;
        for (int t = T_ - 1; t >= 0; --t) {
            out[64 + (size_t)t * 64 + b] = (float)tag;   // path[t, b]
            tag = bp[t][tag];
        }
    }
}

// ---------------------------------------------------------------------------
extern "C" void kernel_launch(void* const* d_in, const int* in_sizes, int n_in,
                              void* d_out, int out_size, void* d_ws, size_t ws_size,
                              hipStream_t stream) {
    const int*   sentence = (const int*)d_in[0];
    const float* emb      = (const float*)d_in[1];
    const float* w_ih_f   = (const float*)d_in[2];
    const float* w_hh_f   = (const float*)d_in[3];
    const float* b_f      = (const float*)d_in[4];
    const float* w_ih_b   = (const float*)d_in[5];
    const float* w_hh_b   = (const float*)d_in[6];
    const float* b_b      = (const float*)d_in[7];
    const float* w_out    = (const float*)d_in[8];
    const float* b_out    = (const float*)d_in[9];
    const float* trans    = (const float*)d_in[10];
    float* out = (float*)d_out;

    // workspace layout: gin fp16 (2 x 64MB) | hf fp32 | hb fp32 | feats fp32
    // total ~203.4 MB
    _Float16* gin_f = (_Float16*)d_ws;
    _Float16* gin_b = gin_f + (size_t)T_ * B_ * G_;      // 33,554,432 halves
    float* hf    = (float*)(gin_b + (size_t)T_ * B_ * G_);
    float* hb    = hf + (size_t)T_ * B_ * H_;
    float* feats = hb + (size_t)T_ * B_ * H_;

    gates_gemm<<<dim3(512, 32), 256, 0, stream>>>(sentence, emb, w_ih_f, w_ih_b,
                                                  gin_f, gin_b);
    lstm_persist<<<128, 512, 0, stream>>>(gin_f, gin_b, w_hh_f, w_hh_b,
                                          b_f, b_b, hf, hb);
    feats_proj<<<8192, 256, 0, stream>>>(hf, hb, w_out, b_out, feats);
    viterbi<<<64, 64, 0, stream>>>(feats, trans, out);
}